// Round 11
// baseline (1556.279 us; speedup 1.0000x reference)
//
#include <hip/hip_runtime.h>
#include <hip/hip_bf16.h>

typedef unsigned short u16;
typedef __attribute__((ext_vector_type(8))) short bf16x8;
typedef __attribute__((ext_vector_type(4))) float f32x4;
typedef __attribute__((ext_vector_type(4))) unsigned short u16x4;

__device__ __forceinline__ f32x4 mfma16(bf16x8 a, bf16x8 b, f32x4 c) {
  return __builtin_amdgcn_mfma_f32_16x16x32_bf16(a, b, c, 0, 0, 0);
}

__device__ __forceinline__ u16 f2bf(float f) {
  unsigned int u = __builtin_bit_cast(unsigned int, f);
  u = (u + 0x7fffu + ((u >> 16) & 1u)) >> 16;
  return (u16)u;
}

__device__ __forceinline__ void gl_lds16(const void* g, void* l) {
  __builtin_amdgcn_global_load_lds(
      (const __attribute__((address_space(1))) void*)g,
      (__attribute__((address_space(3))) void*)l, 16, 0, 0);
}

// ---------------- convert q,k,v fp32 -> bf16 ----------------
__global__ __launch_bounds__(256) void cvt_kernel(
    const float* __restrict__ q, const float* __restrict__ k,
    const float* __restrict__ v, u16* __restrict__ Xq, u16* __restrict__ Xk,
    u16* __restrict__ Xv) {
  const float* src;
  u16* dst;
  int z = blockIdx.y;
  if (z == 0) { src = q; dst = Xq; }
  else if (z == 1) { src = k; dst = Xk; }
  else { src = v; dst = Xv; }
  size_t i = ((size_t)blockIdx.x * 256 + threadIdx.x) * 4;
  float4 f = *(const float4*)(src + i);
  u16x4 o = {f2bf(f.x), f2bf(f.y), f2bf(f.z), f2bf(f.w)};
  *(u16x4*)(dst + i) = o;
}

// ---------------- transpose weights fp32[K][N] -> bf16[N][K] ----------------
__global__ __launch_bounds__(256) void transw_kernel(
    const float* __restrict__ Wq, const float* __restrict__ Wk,
    const float* __restrict__ Wv, const float* __restrict__ Wo,
    u16* __restrict__ Wqt, u16* __restrict__ Wkt, u16* __restrict__ Wvt,
    u16* __restrict__ Wot) {
  __shared__ float t[64][65];
  const float* src;
  u16* dst;
  switch (blockIdx.z) {
    case 0: src = Wq; dst = Wqt; break;
    case 1: src = Wk; dst = Wkt; break;
    case 2: src = Wv; dst = Wvt; break;
    default: src = Wo; dst = Wot; break;
  }
  int tk = blockIdx.x * 64, tn = blockIdx.y * 64;
  int c = threadIdx.x & 63, r0 = (threadIdx.x >> 6) * 16;
  for (int i = 0; i < 16; i++)
    t[r0 + i][c] = src[(size_t)(tk + r0 + i) * 1024 + tn + c];
  __syncthreads();
  for (int i = 0; i < 16; i++)
    dst[(size_t)(tn + r0 + i) * 1024 + tk + c] = f2bf(t[c][r0 + i]);
}

// ---------------- GEMM 8192x1024x1024, A[M,K] bf16, Bt[N,K] bf16 ----------------
// MODE: 0=Q (bias, *0.125, -> Qh[B,H,S,64]) 1=K (bias -> Kh[B,H,S,64])
//       2=V (bias -> Vt[B,H,64,S])          3=O (bias -> f32 out[M,N])
template <int MODE>
__global__ __launch_bounds__(256, 2) void gemm_kernel(
    const u16* __restrict__ A, const u16* __restrict__ Bt,
    const float* __restrict__ bias, void* __restrict__ out) {
  __shared__ __attribute__((aligned(128))) char lds[32768];
  char* As = lds;
  char* Bs = lds + 16384;
  const int tid = threadIdx.x, lane = tid & 63, wv = tid >> 6;
  const int wr = wv >> 1, wc = wv & 1;
  const int m0 = blockIdx.x * 128, n0 = blockIdx.y * 128;
  const int lq = lane >> 4, lr = lane & 15;
  f32x4 acc[4][4] = {};
  const char* Ab = (const char*)A + (size_t)m0 * 2048;
  const char* Bb = (const char*)Bt + (size_t)n0 * 2048;
  for (int kt = 0; kt < 16; ++kt) {
    __syncthreads();
    for (int i = 0; i < 4; ++i) {
      int chunk = (wv * 4 + i) * 1024;
      int L = chunk + lane * 16;
      int row = L >> 7;
      int cb = (L & 127) ^ ((row & 7) << 4);
      gl_lds16(Ab + (size_t)row * 2048 + kt * 128 + cb, As + chunk);
      gl_lds16(Bb + (size_t)row * 2048 + kt * 128 + cb, Bs + chunk);
    }
    __syncthreads();
    bf16x8 af[4][2], bfr[4][2];
    for (int mi = 0; mi < 4; mi++)
      for (int ks = 0; ks < 2; ks++) {
        int row = wr * 64 + mi * 16 + lr;
        int cb = (ks * 64 + lq * 16) ^ ((row & 7) << 4);
        af[mi][ks] = *(const bf16x8*)(As + row * 128 + cb);
      }
    for (int nj = 0; nj < 4; nj++)
      for (int ks = 0; ks < 2; ks++) {
        int row = wc * 64 + nj * 16 + lr;
        int cb = (ks * 64 + lq * 16) ^ ((row & 7) << 4);
        bfr[nj][ks] = *(const bf16x8*)(Bs + row * 128 + cb);
      }
    for (int mi = 0; mi < 4; mi++)
      for (int nj = 0; nj < 4; nj++) {
        acc[mi][nj] = mfma16(af[mi][0], bfr[nj][0], acc[mi][nj]);
        acc[mi][nj] = mfma16(af[mi][1], bfr[nj][1], acc[mi][nj]);
      }
  }
  for (int mi = 0; mi < 4; mi++)
    for (int nj = 0; nj < 4; nj++) {
      int m = m0 + wr * 64 + mi * 16 + lq * 4;
      int col = n0 + wc * 64 + nj * 16 + lr;
      float bval = bias[col];
      if constexpr (MODE == 3) {
        float* O = (float*)out;
        for (int r = 0; r < 4; r++)
          O[(size_t)(m + r) * 1024 + col] = acc[mi][nj][r] + bval;
      } else if constexpr (MODE == 2) {
        u16* O = (u16*)out;
        int b = m >> 11, s = m & 2047;
        int h = col >> 6, dv = col & 63;
        u16x4 pk;
        for (int r = 0; r < 4; r++) pk[r] = f2bf(acc[mi][nj][r] + bval);
        *(u16x4*)(O + ((size_t)((b * 16 + h) * 64 + dv)) * 2048 + s) = pk;
      } else {
        u16* O = (u16*)out;
        int h = col >> 6, dk = col & 63;
        for (int r = 0; r < 4; r++) {
          int mm = m + r;
          int b = mm >> 11, s = mm & 2047;
          float v = acc[mi][nj][r] + bval;
          if constexpr (MODE == 0) v *= 0.125f;
          O[((size_t)((b * 16 + h) * 2048 + s)) * 64 + dk] = f2bf(v);
        }
      }
    }
}

// ---------------- fused attention ----------------
// grid 1024 blocks = (16 qblocks x 64 bh); block 256 (4 waves x 32 q-rows)
// XCD swizzle (T1): lin%8 = XCD (HW round-robin assumption); chunked remap
// swz = (lin&7)*128 + lin>>3 gives each XCD a contiguous 128-block chunk
// = 8 bh values -> K/V read by exactly one XCD's L2 (bijective: 1024=8*128).
// LDS: Ks 16K (128x128B swz) | Vs 16K (64x256B swz) | Ps 4x(32x80B)
// Ps stride MUST stay ≡0 mod 16 (b128 fragment reads); 80 = 5*16.
// Write-side conflicts at stride 80 are 2-way only (same-dword lr pairs
// merge; lq groups land same-bank/different-dword) => free per m136.
__global__ __launch_bounds__(256, 2) void attn_kernel(
    const u16* __restrict__ Qh, const u16* __restrict__ Kh,
    const u16* __restrict__ Vt, u16* __restrict__ att_out,
    float* __restrict__ attn_out) {
  __shared__ __attribute__((aligned(128))) char lds[43008];
  char* Ks = lds;
  char* Vs = lds + 16384;
  const int tid = threadIdx.x, lane = tid & 63, wv = tid >> 6;
  char* Ps = lds + 32768 + wv * 2560;  // per-wave P tile [32][stride 80B]
  const int lin = blockIdx.x + (blockIdx.y << 4);
  const int swz = ((lin & 7) << 7) + (lin >> 3);
  const int bh = swz >> 4;
  const int q0 = (swz & 15) * 128 + wv * 32;
  const u16* Qb = Qh + (size_t)bh * 2048 * 64;
  const char* Kb = (const char*)(Kh + (size_t)bh * 2048 * 64);
  const char* Vb = (const char*)(Vt + (size_t)bh * 64 * 2048);
  const int lq = lane >> 4, lr = lane & 15;

  bf16x8 qa[2][2];
  for (int mi = 0; mi < 2; mi++)
    for (int ks = 0; ks < 2; ks++)
      qa[mi][ks] =
          *(const bf16x8*)(Qb + ((size_t)(q0 + mi * 16 + lr)) * 64 + ks * 32 + lq * 8);

  f32x4 o[2][4] = {};
  float lacc[2][4] = {};

  // ---- loop A: l accumulation + O' = exp(S) @ V ----
  for (int kt = 0; kt < 16; ++kt) {
    __syncthreads();
    for (int i = 0; i < 4; ++i) {
      int chunk = (wv * 4 + i) * 1024;
      int L = chunk + lane * 16;
      {
        int row = L >> 7;
        int cb = (L & 127) ^ ((row & 7) << 4);
        gl_lds16(Kb + (size_t)(kt * 128 + row) * 128 + cb, Ks + chunk);
      }
      {
        int row = L >> 8;
        int cb = (L & 255) ^ ((row & 7) << 4);
        gl_lds16(Vb + (size_t)row * 4096 + kt * 256 + cb, Vs + chunk);
      }
    }
    __syncthreads();
    for (int c = 0; c < 4; c++) {
      bf16x8 kb[2][2];
      for (int nl = 0; nl < 2; nl++)
        for (int ks = 0; ks < 2; ks++) {
          int row = (c * 2 + nl) * 16 + lr;
          int cb = (ks * 64 + lq * 16) ^ ((row & 7) << 4);
          kb[nl][ks] = *(const bf16x8*)(Ks + row * 128 + cb);
        }
      f32x4 sc[2][2];
      for (int mi = 0; mi < 2; mi++)
        for (int nl = 0; nl < 2; nl++) {
          f32x4 s = {};
          s = mfma16(qa[mi][0], kb[nl][0], s);
          s = mfma16(qa[mi][1], kb[nl][1], s);
          sc[mi][nl] = s;
        }
      for (int mi = 0; mi < 2; mi++)
        for (int nl = 0; nl < 2; nl++)
          for (int r = 0; r < 4; r++) {
            float p = __expf(sc[mi][nl][r]);
            lacc[mi][r] += p;
            int row = mi * 16 + lq * 4 + r;
            *(u16*)(Ps + row * 80 + (nl * 16 + lr) * 2) = f2bf(p);
          }
      bf16x8 pa[2], vbf[4];
      for (int mi = 0; mi < 2; mi++) {
        int row = mi * 16 + lr;
        pa[mi] = *(const bf16x8*)(Ps + row * 80 + lq * 16);
      }
      for (int dj = 0; dj < 4; dj++) {
        int row = dj * 16 + lr;
        int cb = (c * 64 + lq * 16) ^ ((row & 7) << 4);
        vbf[dj] = *(const bf16x8*)(Vs + row * 256 + cb);
      }
      for (int mi = 0; mi < 2; mi++)
        for (int dj = 0; dj < 4; dj++)
          o[mi][dj] = mfma16(pa[mi], vbf[dj], o[mi][dj]);
    }
  }

  // reduce row-sums across the 16-lane col groups
  float rl[2][4];
  for (int mi = 0; mi < 2; mi++)
    for (int r = 0; r < 4; r++) {
      float s = lacc[mi][r];
      s += __shfl_xor(s, 1);
      s += __shfl_xor(s, 2);
      s += __shfl_xor(s, 4);
      s += __shfl_xor(s, 8);
      rl[mi][r] = 1.0f / s;
    }

  // write att_out [B*S, H*DV] bf16
  const int b = bh >> 4, h = bh & 15;
  for (int mi = 0; mi < 2; mi++)
    for (int dj = 0; dj < 4; dj++)
      for (int r = 0; r < 4; r++) {
        int s_row = q0 + mi * 16 + lq * 4 + r;
        int col = h * 64 + dj * 16 + lr;
        att_out[((size_t)(b * 2048 + s_row)) * 1024 + col] =
            f2bf(o[mi][dj][r] * rl[mi][r]);
      }

  // ---- loop B: recompute scores, write normalized attn ----
  float* attn_bh = attn_out + (size_t)bh * 2048 * 2048;
  for (int kt = 0; kt < 16; ++kt) {
    __syncthreads();
    for (int i = 0; i < 4; ++i) {
      int chunk = (wv * 4 + i) * 1024;
      int L = chunk + lane * 16;
      int row = L >> 7;
      int cb = (L & 127) ^ ((row & 7) << 4);
      gl_lds16(Kb + (size_t)(kt * 128 + row) * 128 + cb, Ks + chunk);
    }
    __syncthreads();
    for (int c = 0; c < 4; c++) {
      bf16x8 kb[2][2];
      for (int nl = 0; nl < 2; nl++)
        for (int ks = 0; ks < 2; ks++) {
          int row = (c * 2 + nl) * 16 + lr;
          int cb = (ks * 64 + lq * 16) ^ ((row & 7) << 4);
          kb[nl][ks] = *(const bf16x8*)(Ks + row * 128 + cb);
        }
      for (int mi = 0; mi < 2; mi++)
        for (int nl = 0; nl < 2; nl++) {
          f32x4 s = {};
          s = mfma16(qa[mi][0], kb[nl][0], s);
          s = mfma16(qa[mi][1], kb[nl][1], s);
          for (int r = 0; r < 4; r++) {
            float p = __expf(s[r]) * rl[mi][r];
            int s_row = q0 + mi * 16 + lq * 4 + r;
            int kcol = kt * 128 + c * 32 + nl * 16 + lr;
            attn_bh[(size_t)s_row * 2048 + kcol] = p;
          }
        }
    }
  }
}

extern "C" void kernel_launch(void* const* d_in, const int* in_sizes, int n_in,
                              void* d_out, int out_size, void* d_ws,
                              size_t ws_size, hipStream_t stream) {
  const float* q = (const float*)d_in[0];
  const float* k = (const float*)d_in[1];
  const float* v = (const float*)d_in[2];
  const float* Wq = (const float*)d_in[3];
  const float* bq = (const float*)d_in[4];
  const float* Wk = (const float*)d_in[5];
  const float* bk = (const float*)d_in[6];
  const float* Wv = (const float*)d_in[7];
  const float* bv = (const float*)d_in[8];
  const float* Wo = (const float*)d_in[9];
  const float* bo = (const float*)d_in[10];
  char* ws = (char*)d_ws;
  // Tight aliased packing (all aliases stream-ordered; producers never
  // read the slot they write). Peak d_ws use = 72 MB.
  u16* Xq  = (u16*)(ws + 0);         // [0,16M)  live: cvt -> gemm<0>
  u16* Xk  = (u16*)(ws + 16777216);  // [16,32M) live: cvt -> gemm<1>
  u16* Xv  = (u16*)(ws + 33554432);  // [32,48M) live: cvt -> gemm<2>
  u16* Wqt = (u16*)(ws + 50331648);  // [48,50M)
  u16* Wkt = (u16*)(ws + 52428800);  // [50,52M)
  u16* Wvt = (u16*)(ws + 54525952);  // [52,54M)
  u16* Wot = (u16*)(ws + 56623104);  // [54,56M)
  u16* Qh  = (u16*)(ws + 58720256);  // [56,72M) live: gemm<0> -> attn
  u16* Kh  = (u16*)(ws + 0);         // aliases Xq (dead after gemm<0>)
  u16* Vt  = (u16*)(ws + 16777216);  // aliases Xk (dead after gemm<1>)
  u16* Ao  = (u16*)(ws + 33554432);  // aliases Xv (dead after gemm<2>)
  float* out = (float*)d_out;
  float* attn = out + 8388608;

  cvt_kernel<<<dim3(8192, 3), 256, 0, stream>>>(q, k, v, Xq, Xk, Xv);
  transw_kernel<<<dim3(16, 16, 4), 256, 0, stream>>>(Wq, Wk, Wv, Wo, Wqt, Wkt,
                                                     Wvt, Wot);
  gemm_kernel<0><<<dim3(64, 8), 256, 0, stream>>>(Xq, Wqt, bq, Qh);
  gemm_kernel<1><<<dim3(64, 8), 256, 0, stream>>>(Xk, Wkt, bk, Kh);
  gemm_kernel<2><<<dim3(64, 8), 256, 0, stream>>>(Xv, Wvt, bv, Vt);
  attn_kernel<<<dim3(16, 64), 256, 0, stream>>>(Qh, Kh, Vt, Ao, attn);
  gemm_kernel<3><<<dim3(64, 8), 256, 0, stream>>>(Ao, Wot, bo, out);
}